// Round 9
// baseline (151.166 us; speedup 1.0000x reference)
//
#include <hip/hip_runtime.h>

#define T_FRAMES 2400
#define V 25
#define C 128
#define VC 3200          // V*C
#define NB 3
#define GN_EPS 1e-5f
#define MAXDEG 16
#define KS 384           // spatial GEMM1 K = 3*C
#define K2 96            // spatial GEMM2 K (3 branches x 32, v padded 25->32)
#define CSTR 136         // xt row stride (u16): 272B -> 2-way banks (free)
#define KSTR 104         // yb row stride (u16): 208B -> 2-way banks (free)
#define AGG_STRIDE 136   // agg row stride (u16)
#define WMAX 32          // temporal source-window capacity (per frame)

typedef __attribute__((ext_vector_type(8))) short short8;   // 8 bf16 (4 VGPR)
typedef __attribute__((ext_vector_type(4))) float floatx4;  // MFMA accum
typedef unsigned short u16;
typedef unsigned int u32;

__device__ __forceinline__ u16 f2bf(float f) {
    u32 u = __builtin_bit_cast(u32, f);
    u += 0x7FFFu + ((u >> 16) & 1u);          // RNE
    return (u16)(u >> 16);
}
__device__ __forceinline__ float bf2f(u16 h) {
    u32 u = ((u32)h) << 16;
    return __builtin_bit_cast(float, u);
}

// ------------------------------------------------------------------ prep
__global__ __launch_bounds__(256) void k_prep(
        const float* __restrict__ Ws, const float* __restrict__ Wt,
        const float* __restrict__ A, const float* __restrict__ EI,
        const float* __restrict__ bs,
        u16* __restrict__ Wsw, u16* __restrict__ Wtsw, u16* __restrict__ Msw,
        float* __restrict__ bsum, int* __restrict__ deg)
{
    const int idx = blockIdx.x * 256 + threadIdx.x;
    if (idx < KS * C) {
        const int j = idx & 7, n = (idx >> 3) & 127, kg = idx >> 10;
        const int k = kg * 8 + j;
        Wsw[idx] = f2bf(Ws[k * C + n]);
    }
    if (idx < C * C) {
        const int j = idx & 7, n = (idx >> 3) & 127, kg = idx >> 10;
        const int k = kg * 8 + j;
        Wtsw[idx] = f2bf(Wt[k * C + n]);
    }
    if (idx < 32 * K2) {
        const int u = idx / K2, r = idx % K2;
        const int i = r >> 5, v = r & 31;
        float val = 0.f;
        if (u < V && v < V) {
            const int a = (i * V + u) * V + v;
            val = A[a] * EI[a];
        }
        Msw[idx] = f2bf(val);
    }
    if (idx < C) bsum[idx] = bs[idx] + bs[C + idx] + bs[2 * C + idx];
    if (idx < T_FRAMES) deg[idx] = 0;
}

__global__ __launch_bounds__(256) void k_scatter(
        const int* __restrict__ eidx, const float* __restrict__ ew, int E,
        int* __restrict__ deg, int* __restrict__ adjsrc, float* __restrict__ adjw) {
    const int e = blockIdx.x * 256 + threadIdx.x;
    if (e >= E) return;
    const int s = eidx[e];
    const int d = eidx[E + e];
    const int slot = atomicAdd(&deg[d], 1);
    if (slot < MAXDEG) {
        adjsrc[d * MAXDEG + slot] = s;
        adjw  [d * MAXDEG + slot] = ew[e];
    }
}

// ---------------- spatial: all-MFMA, 1 frame/block, 3 barriers -----------
// 2400 blocks. Register structure fits the hard 64-VGPR budget: rolled
// branch loop (wfr streamed), transient mfr, no cross-phase residents.
__global__ __launch_bounds__(512) void k_spatial(
        const float* __restrict__ x, const u16* __restrict__ Wsw,
        const u16* __restrict__ Msw, const float* __restrict__ bsum_g,
        const float* __restrict__ gamma_g, const float* __restrict__ beta_g,
        u16* __restrict__ h_g)
{
    __shared__ u16 xt[32 * CSTR];     // 8.7 KB  (bf16 x, rows 25-31 zero)
    __shared__ u16 yb[C * KSTR];      // 26.6 KB (Y^T: yb[d][k2])
    __shared__ float redS[8], redQ[8];

    const int tid = threadIdx.x;
    const int w   = tid >> 6;        // wave -> 16-col tile of d
    const int l   = tid & 63;
    const int q   = l >> 4;
    const int ln  = l & 15;
    const int col = w * 16 + ln;
    const int t   = blockIdx.x;

    for (int i = tid; i < 7 * CSTR; i += 512) xt[25 * CSTR + i] = 0;

    const float bsv = bsum_g[col];

    // stage x[t] as bf16 into xt (400 threads x 8 u16)
    if (tid < 400) {
        const int srow = tid >> 4;
        const int sc0  = (tid & 15) * 8;
        const float* xp = x + (size_t)t * VC + srow * C + sc0;
        const float4 v0 = *(const float4*)xp;
        const float4 v1 = *(const float4*)(xp + 4);
        u32 pk[4];
        pk[0] = (u32)f2bf(v0.x) | ((u32)f2bf(v0.y) << 16);
        pk[1] = (u32)f2bf(v0.z) | ((u32)f2bf(v0.w) << 16);
        pk[2] = (u32)f2bf(v1.x) | ((u32)f2bf(v1.y) << 16);
        pk[3] = (u32)f2bf(v1.z) | ((u32)f2bf(v1.w) << 16);
        *reinterpret_cast<uint4*>(&xt[srow * CSTR + sc0]) = *reinterpret_cast<uint4*>(pk);
    }
    __syncthreads();   // (A) xt ready

    // ---- GEMM1^T: Y^T_i = Ws_i^T @ x^T, branch-sequential, loop ROLLED
    #pragma unroll 1
    for (int i = 0; i < 3; i++) {
        short8 wfr[4];
        #pragma unroll
        for (int s = 0; s < 4; s++)
            wfr[s] = *reinterpret_cast<const short8*>(
                Wsw + (((i * 4 + s) * 4 + q) * C + col) * 8);
        floatx4 ta = {0,0,0,0}, tb = {0,0,0,0};
        #pragma unroll
        for (int s = 0; s < 4; s++) {
            const short8 bx0 = *reinterpret_cast<const short8*>(&xt[ln * CSTR + s * 32 + q * 8]);
            const short8 bx1 = *reinterpret_cast<const short8*>(&xt[(16 + ln) * CSTR + s * 32 + q * 8]);
            ta = __builtin_amdgcn_mfma_f32_16x16x32_bf16(wfr[s], bx0, ta, 0, 0, 0);
            tb = __builtin_amdgcn_mfma_f32_16x16x32_bf16(wfr[s], bx1, tb, 0, 0, 0);
        }
        // D[m=q*4+r][n=ln]: d=w*16+q*4+r, v=ln (+16). Pad v>=25 computes 0.
        #pragma unroll
        for (int r = 0; r < 4; r++) {
            const int d = w * 16 + q * 4 + r;
            yb[d * KSTR + i * 32 + ln]      = f2bf(ta[r]);
            yb[d * KSTR + i * 32 + 16 + ln] = f2bf(tb[r]);
        }
    }
    __syncthreads();   // (B) yb ready

    // ---- GEMM2: h = M @ Y  (mfr transient)
    floatx4 h0 = {0,0,0,0}, h1 = {0,0,0,0};
    {
        short8 mfr[2][3];
        #pragma unroll
        for (int tile = 0; tile < 2; tile++)
            #pragma unroll
            for (int i2 = 0; i2 < 3; i2++)
                mfr[tile][i2] = *reinterpret_cast<const short8*>(
                    Msw + (tile * 16 + ln) * K2 + i2 * 32 + q * 8);
        #pragma unroll
        for (int i2 = 0; i2 < 3; i2++) {
            const short8 b2 = *reinterpret_cast<const short8*>(&yb[col * KSTR + i2 * 32 + q * 8]);
            h0 = __builtin_amdgcn_mfma_f32_16x16x32_bf16(mfr[0][i2], b2, h0, 0, 0, 0);
            h1 = __builtin_amdgcn_mfma_f32_16x16x32_bf16(mfr[1][i2], b2, h1, 0, 0, 0);
        }
    }

    // ---- bias + GN stats (mask pad rows >= 25)
    float s_p = 0.f, q_p = 0.f;
    #pragma unroll
    for (int r = 0; r < 4; r++) {
        h0[r] += bsv;
        s_p += h0[r]; q_p = fmaf(h0[r], h0[r], q_p);
    }
    #pragma unroll
    for (int r = 0; r < 4; r++) {
        h1[r] += bsv;
        if (q * 4 + r < 9) { s_p += h1[r]; q_p = fmaf(h1[r], h1[r], q_p); }
    }
    #pragma unroll
    for (int off = 32; off; off >>= 1) {
        s_p += __shfl_down(s_p, off);
        q_p += __shfl_down(q_p, off);
    }
    if (l == 0) { redS[w] = s_p; redQ[w] = q_p; }
    __syncthreads();   // (C) partials ready

    float S = 0.f, Q = 0.f;
    #pragma unroll
    for (int i = 0; i < 8; i++) { S += redS[i]; Q += redQ[i]; }
    const float mu  = S / (float)VC;
    const float var = Q / (float)VC - mu * mu;
    const float rs  = rsqrtf(fmaxf(var, 0.f) + GN_EPS);

    u16* hp = h_g + (size_t)t * VC;
    #pragma unroll
    for (int r = 0; r < 4; r++) {
        const int idx = (q * 4 + r) * C + col;
        const float v = (h0[r] - mu) * rs * gamma_g[idx] + beta_g[idx];
        hp[idx] = f2bf(v > 0.f ? v : 0.f);
    }
    #pragma unroll
    for (int r = 0; r < 4; r++) {
        const int row = 16 + q * 4 + r;
        if (row < V) {
            const int idx = row * C + col;
            const float v = (h1[r] - mu) * rs * gamma_g[idx] + beta_g[idx];
            hp[idx] = f2bf(v > 0.f ? v : 0.f);
        }
    }
}

// ------------- temporal: 1 frame/block windowed gather + MFMA ------------
// 2400 blocks. Window (<=WMAX consecutive source frames) collapsed to one
// weight vector; 400-thread gather with 8 accum regs; 8 MFMAs/wave epilogue.
__global__ __launch_bounds__(512) void k_temporal(
        const u16* __restrict__ h, const int* __restrict__ deg,
        const int* __restrict__ adjsrc, const float* __restrict__ adjw,
        const u16* __restrict__ Wtsw, const float* __restrict__ bt,
        float* __restrict__ out)
{
    __shared__ u16   agg[32 * AGG_STRIDE];   // 8.7 KB
    __shared__ float wvec[WMAX];
    __shared__ int   s_src[MAXDEG];
    __shared__ float s_wv[MAXDEG];
    __shared__ int   s_info[3];              // deg, minS, nsrc

    const int tid = threadIdx.x;
    const int w   = tid >> 6;
    const int l   = tid & 63;
    const int q   = l >> 4;
    const int ln  = l & 15;
    const int col = w * 16 + ln;
    const int t   = blockIdx.x;

    if (tid < MAXDEG) {
        s_src[tid] = adjsrc[t * MAXDEG + tid];
        s_wv[tid]  = adjw  [t * MAXDEG + tid];
    }
    if (tid == MAXDEG) s_info[0] = min(deg[t], MAXDEG);
    if (tid >= 32 && tid < 32 + WMAX) wvec[tid - 32] = 0.f;
    // zero agg pad rows (25..31)
    for (int i = tid; i < 7 * AGG_STRIDE; i += 512) agg[25 * AGG_STRIDE + i] = 0;
    __syncthreads();

    const int dg = s_info[0];
    // window min/max over first wave's first 16 lanes
    if (tid < 16) {
        const bool valid = tid < dg;
        int sv = valid ? s_src[tid] : 0x7fffffff;
        int sx = valid ? s_src[tid] : (int)0x80000000;
        #pragma unroll
        for (int off = 8; off; off >>= 1) {
            sv = min(sv, __shfl_down(sv, off));
            sx = max(sx, __shfl_down(sx, off));
        }
        if (tid == 0) {
            s_info[1] = sv;
            s_info[2] = (sx >= sv) ? (sx - sv + 1) : 0;
        }
    }
    __syncthreads();
    const int minS = s_info[1];
    const int nsrc = s_info[2];
    const bool windowed = (nsrc > 0) && (nsrc <= WMAX);
    if (windowed && tid < dg) atomicAdd(&wvec[s_src[tid] - minS], s_wv[tid]);
    __syncthreads();   // wvec ready

    // gather: thread owns one (row, c8) unit
    if (tid < V * 16) {
        const int row = tid >> 4;
        const int c8  = (tid & 15) * 8;
        float a0[8] = {0,0,0,0,0,0,0,0};
        if (windowed) {
            const u16* hb = h + (size_t)minS * VC + row * C + c8;
            for (int s = 0; s < nsrc; s++) {
                const short8 hv = *reinterpret_cast<const short8*>(hb + (size_t)s * VC);
                const float wv = wvec[s];
                #pragma unroll
                for (int j = 0; j < 8; j++) a0[j] = fmaf(wv, bf2f((u16)hv[j]), a0[j]);
            }
        } else {
            for (int e = 0; e < dg; e++) {
                const short8 hv = *reinterpret_cast<const short8*>(
                    h + (size_t)s_src[e] * VC + row * C + c8);
                const float wv = s_wv[e];
                #pragma unroll
                for (int j = 0; j < 8; j++) a0[j] = fmaf(wv, bf2f((u16)hv[j]), a0[j]);
            }
        }
        u32 pk[4];
        #pragma unroll
        for (int i = 0; i < 4; i++)
            pk[i] = (u32)f2bf(a0[2 * i]) | ((u32)f2bf(a0[2 * i + 1]) << 16);
        *reinterpret_cast<uint4*>(&agg[row * AGG_STRIDE + c8]) =
            *reinterpret_cast<uint4*>(pk);
    }
    __syncthreads();

    // MFMA epilogue (bfr transient)
    short8 bfr[4];
    #pragma unroll
    for (int s = 0; s < 4; s++)
        bfr[s] = *reinterpret_cast<const short8*>(Wtsw + ((s * 4 + q) * C + col) * 8);
    const float btv = bt[col];

    floatx4 acc0 = {0,0,0,0}, acc1 = {0,0,0,0};
    #pragma unroll
    for (int s = 0; s < 4; s++) {
        const short8 a0 = *reinterpret_cast<const short8*>(&agg[ln * AGG_STRIDE + s * 32 + q * 8]);
        const short8 a1 = *reinterpret_cast<const short8*>(&agg[(16 + ln) * AGG_STRIDE + s * 32 + q * 8]);
        acc0 = __builtin_amdgcn_mfma_f32_16x16x32_bf16(a0, bfr[s], acc0, 0, 0, 0);
        acc1 = __builtin_amdgcn_mfma_f32_16x16x32_bf16(a1, bfr[s], acc1, 0, 0, 0);
    }
    float* op = out + (size_t)t * VC;
    #pragma unroll
    for (int r = 0; r < 4; r++) {
        const float v = acc0[r] + btv;
        op[(q * 4 + r) * C + col] = v > 0.f ? v : 0.f;
    }
    #pragma unroll
    for (int r = 0; r < 4; r++) {
        const int row = 16 + q * 4 + r;
        if (row < V) {
            const float v = acc1[r] + btv;
            op[row * C + col] = v > 0.f ? v : 0.f;
        }
    }
}

// ---------------------------------------------------------------- launcher
extern "C" void kernel_launch(void* const* d_in, const int* in_sizes, int n_in,
                              void* d_out, int out_size, void* d_ws, size_t ws_size,
                              hipStream_t stream) {
    const float* x     = (const float*)d_in[0];
    const float* A     = (const float*)d_in[1];
    const float* EI    = (const float*)d_in[2];
    const float* Ws    = (const float*)d_in[3];
    const float* bs    = (const float*)d_in[4];
    const float* Wt    = (const float*)d_in[5];
    const float* bt    = (const float*)d_in[6];
    const float* gamma = (const float*)d_in[7];
    const float* beta  = (const float*)d_in[8];
    const float* ew    = (const float*)d_in[9];
    const int*   eidx  = (const int*)d_in[10];
    const int E = in_sizes[9];

    char* ws = (char*)d_ws;
    u16*   h      = (u16*)(ws);                  // 15,360,000 B
    u16*   Wsw    = (u16*)(ws + 15360000);       // 98,304 B
    u16*   Wtsw   = (u16*)(ws + 15458304);       // 32,768 B
    u16*   Msw    = (u16*)(ws + 15491072);       // 6,144 B
    float* bsum   = (float*)(ws + 15497216);     // 512 B
    int*   deg    = (int*)(ws + 15497728);       // 9,600 B
    int*   adjsrc = (int*)(ws + 15507328);       // 153,600 B
    float* adjw   = (float*)(ws + 15660928);     // 153,600 B

    float* out = (float*)d_out;

    k_prep<<<(KS * C + 255) / 256, 256, 0, stream>>>(Ws, Wt, A, EI, bs, Wsw, Wtsw, Msw, bsum, deg);
    k_scatter<<<(E + 255) / 256, 256, 0, stream>>>(eidx, ew, E, deg, adjsrc, adjw);
    k_spatial<<<T_FRAMES, 512, 0, stream>>>(x, Wsw, Msw, bsum, gamma, beta, h);
    k_temporal<<<T_FRAMES, 512, 0, stream>>>(h, deg, adjsrc, adjw, Wtsw, bt, out);
}

// Round 10
// 138.381 us; speedup vs baseline: 1.0924x; 1.0924x over previous
//
#include <hip/hip_runtime.h>

#define T_FRAMES 2400
#define V 25
#define C 128
#define VC 3200          // V*C
#define NB 3
#define GN_EPS 1e-5f
#define MAXDEG 16
#define KS 384           // spatial GEMM1 K = 3*C
#define K2 96            // spatial GEMM2 K (3 branches x 32, v padded 25->32)
#define CSTR 136         // xt row stride (u16): 272B -> 2-way banks (free)
#define KSTR 104         // yb row stride (u16): 208B -> 2-way banks (free)
#define AGG_STRIDE 136   // agg row stride (u16)
#define FPB 4            // frames per block (temporal)
#define WMAX 48          // temporal source-window capacity

typedef __attribute__((ext_vector_type(8))) short short8;   // 8 bf16 (4 VGPR)
typedef __attribute__((ext_vector_type(4))) float floatx4;  // MFMA accum
typedef unsigned short u16;
typedef unsigned int u32;

__device__ __forceinline__ u16 f2bf(float f) {
    u32 u = __builtin_bit_cast(u32, f);
    u += 0x7FFFu + ((u >> 16) & 1u);          // RNE
    return (u16)(u >> 16);
}
__device__ __forceinline__ float bf2f(u16 h) {
    u32 u = ((u32)h) << 16;
    return __builtin_bit_cast(float, u);
}

// ------------------------------------------------------------------ prep
__global__ __launch_bounds__(256) void k_prep(
        const float* __restrict__ Ws, const float* __restrict__ Wt,
        const float* __restrict__ A, const float* __restrict__ EI,
        const float* __restrict__ bs,
        u16* __restrict__ Wsw, u16* __restrict__ Wtsw, u16* __restrict__ Msw,
        float* __restrict__ bsum, int* __restrict__ deg)
{
    const int idx = blockIdx.x * 256 + threadIdx.x;
    if (idx < KS * C) {
        const int j = idx & 7, n = (idx >> 3) & 127, kg = idx >> 10;
        const int k = kg * 8 + j;
        Wsw[idx] = f2bf(Ws[k * C + n]);
    }
    if (idx < C * C) {
        const int j = idx & 7, n = (idx >> 3) & 127, kg = idx >> 10;
        const int k = kg * 8 + j;
        Wtsw[idx] = f2bf(Wt[k * C + n]);
    }
    if (idx < 32 * K2) {
        const int u = idx / K2, r = idx % K2;
        const int i = r >> 5, v = r & 31;
        float val = 0.f;
        if (u < V && v < V) {
            const int a = (i * V + u) * V + v;
            val = A[a] * EI[a];
        }
        Msw[idx] = f2bf(val);
    }
    if (idx < C) bsum[idx] = bs[idx] + bs[C + idx] + bs[2 * C + idx];
    if (idx < T_FRAMES) deg[idx] = 0;
}

__global__ __launch_bounds__(256) void k_scatter(
        const int* __restrict__ eidx, const float* __restrict__ ew, int E,
        int* __restrict__ deg, int* __restrict__ adjsrc, float* __restrict__ adjw) {
    const int e = blockIdx.x * 256 + threadIdx.x;
    if (e >= E) return;
    const int s = eidx[e];
    const int d = eidx[E + e];
    const int slot = atomicAdd(&deg[d], 1);
    if (slot < MAXDEG) {
        adjsrc[d * MAXDEG + slot] = s;
        adjw  [d * MAXDEG + slot] = ew[e];
    }
}

// ---------------- spatial: all-MFMA, 1 frame/block, 3 barriers -----------
// 2400 blocks. Register structure fits the hard 64-VGPR budget: rolled
// branch loop (wfr streamed), transient mfr, no cross-phase residents.
// mfr loads hoisted above barrier (B): no yb dependence, L2 latency hides
// under the barrier drain.
__global__ __launch_bounds__(512) void k_spatial(
        const float* __restrict__ x, const u16* __restrict__ Wsw,
        const u16* __restrict__ Msw, const float* __restrict__ bsum_g,
        const float* __restrict__ gamma_g, const float* __restrict__ beta_g,
        u16* __restrict__ h_g)
{
    __shared__ u16 xt[32 * CSTR];     // 8.7 KB  (bf16 x, rows 25-31 zero)
    __shared__ u16 yb[C * KSTR];      // 26.6 KB (Y^T: yb[d][k2])
    __shared__ float redS[8], redQ[8];

    const int tid = threadIdx.x;
    const int w   = tid >> 6;        // wave -> 16-col tile of d
    const int l   = tid & 63;
    const int q   = l >> 4;
    const int ln  = l & 15;
    const int col = w * 16 + ln;
    const int t   = blockIdx.x;

    for (int i = tid; i < 7 * CSTR; i += 512) xt[25 * CSTR + i] = 0;

    const float bsv = bsum_g[col];

    // stage x[t] as bf16 into xt (400 threads x 8 u16)
    if (tid < 400) {
        const int srow = tid >> 4;
        const int sc0  = (tid & 15) * 8;
        const float* xp = x + (size_t)t * VC + srow * C + sc0;
        const float4 v0 = *(const float4*)xp;
        const float4 v1 = *(const float4*)(xp + 4);
        u32 pk[4];
        pk[0] = (u32)f2bf(v0.x) | ((u32)f2bf(v0.y) << 16);
        pk[1] = (u32)f2bf(v0.z) | ((u32)f2bf(v0.w) << 16);
        pk[2] = (u32)f2bf(v1.x) | ((u32)f2bf(v1.y) << 16);
        pk[3] = (u32)f2bf(v1.z) | ((u32)f2bf(v1.w) << 16);
        *reinterpret_cast<uint4*>(&xt[srow * CSTR + sc0]) = *reinterpret_cast<uint4*>(pk);
    }
    __syncthreads();   // (A) xt ready

    // ---- GEMM1^T: Y^T_i = Ws_i^T @ x^T, branch-sequential, loop ROLLED
    #pragma unroll 1
    for (int i = 0; i < 3; i++) {
        short8 wfr[4];
        #pragma unroll
        for (int s = 0; s < 4; s++)
            wfr[s] = *reinterpret_cast<const short8*>(
                Wsw + (((i * 4 + s) * 4 + q) * C + col) * 8);
        floatx4 ta = {0,0,0,0}, tb = {0,0,0,0};
        #pragma unroll
        for (int s = 0; s < 4; s++) {
            const short8 bx0 = *reinterpret_cast<const short8*>(&xt[ln * CSTR + s * 32 + q * 8]);
            const short8 bx1 = *reinterpret_cast<const short8*>(&xt[(16 + ln) * CSTR + s * 32 + q * 8]);
            ta = __builtin_amdgcn_mfma_f32_16x16x32_bf16(wfr[s], bx0, ta, 0, 0, 0);
            tb = __builtin_amdgcn_mfma_f32_16x16x32_bf16(wfr[s], bx1, tb, 0, 0, 0);
        }
        // D[m=q*4+r][n=ln]: d=w*16+q*4+r, v=ln (+16). Pad v>=25 computes 0.
        #pragma unroll
        for (int r = 0; r < 4; r++) {
            const int d = w * 16 + q * 4 + r;
            yb[d * KSTR + i * 32 + ln]      = f2bf(ta[r]);
            yb[d * KSTR + i * 32 + 16 + ln] = f2bf(tb[r]);
        }
    }

    // mfr loads issued BEFORE the barrier (no yb dependence)
    short8 mfr[2][3];
    #pragma unroll
    for (int tile = 0; tile < 2; tile++)
        #pragma unroll
        for (int i2 = 0; i2 < 3; i2++)
            mfr[tile][i2] = *reinterpret_cast<const short8*>(
                Msw + (tile * 16 + ln) * K2 + i2 * 32 + q * 8);
    __syncthreads();   // (B) yb ready

    // ---- GEMM2: h = M @ Y
    floatx4 h0 = {0,0,0,0}, h1 = {0,0,0,0};
    #pragma unroll
    for (int i2 = 0; i2 < 3; i2++) {
        const short8 b2 = *reinterpret_cast<const short8*>(&yb[col * KSTR + i2 * 32 + q * 8]);
        h0 = __builtin_amdgcn_mfma_f32_16x16x32_bf16(mfr[0][i2], b2, h0, 0, 0, 0);
        h1 = __builtin_amdgcn_mfma_f32_16x16x32_bf16(mfr[1][i2], b2, h1, 0, 0, 0);
    }

    // ---- bias + GN stats (mask pad rows >= 25)
    float s_p = 0.f, q_p = 0.f;
    #pragma unroll
    for (int r = 0; r < 4; r++) {
        h0[r] += bsv;
        s_p += h0[r]; q_p = fmaf(h0[r], h0[r], q_p);
    }
    #pragma unroll
    for (int r = 0; r < 4; r++) {
        h1[r] += bsv;
        if (q * 4 + r < 9) { s_p += h1[r]; q_p = fmaf(h1[r], h1[r], q_p); }
    }
    #pragma unroll
    for (int off = 32; off; off >>= 1) {
        s_p += __shfl_down(s_p, off);
        q_p += __shfl_down(q_p, off);
    }
    if (l == 0) { redS[w] = s_p; redQ[w] = q_p; }
    __syncthreads();   // (C) partials ready

    float S = 0.f, Q = 0.f;
    #pragma unroll
    for (int i = 0; i < 8; i++) { S += redS[i]; Q += redQ[i]; }
    const float mu  = S / (float)VC;
    const float var = Q / (float)VC - mu * mu;
    const float rs  = rsqrtf(fmaxf(var, 0.f) + GN_EPS);

    u16* hp = h_g + (size_t)t * VC;
    #pragma unroll
    for (int r = 0; r < 4; r++) {
        const int idx = (q * 4 + r) * C + col;
        const float v = (h0[r] - mu) * rs * gamma_g[idx] + beta_g[idx];
        hp[idx] = f2bf(v > 0.f ? v : 0.f);
    }
    #pragma unroll
    for (int r = 0; r < 4; r++) {
        const int row = 16 + q * 4 + r;
        if (row < V) {
            const int idx = row * C + col;
            const float v = (h1[r] - mu) * rs * gamma_g[idx] + beta_g[idx];
            hp[idx] = f2bf(v > 0.f ? v : 0.f);
        }
    }
}

// ------------------- temporal: windowed gather-sum + MFMA + bias + ReLU
// 600 blocks x 4 frames (R8 config: best measured). Single-pass gather:
// each window frame loaded ONCE, accumulated into all 4 output frames.
__global__ __launch_bounds__(512) void k_temporal(
        const u16* __restrict__ h, const int* __restrict__ deg,
        const int* __restrict__ adjsrc, const float* __restrict__ adjw,
        const u16* __restrict__ Wtsw, const float* __restrict__ bt,
        float* __restrict__ out)
{
    __shared__ u16   agg[FPB * 32 * AGG_STRIDE];   // 34.8 KB
    __shared__ float wmat[FPB][WMAX];
    __shared__ int   s_src[FPB * MAXDEG];
    __shared__ float s_wv[FPB * MAXDEG];
    __shared__ int   s_deg[FPB];
    __shared__ int   s_info[2];                    // minS, nsrc

    const int tid = threadIdx.x;
    const int w   = tid >> 6;
    const int l   = tid & 63;
    const int q   = l >> 4;
    const int ln  = l & 15;
    const int col = w * 16 + ln;
    const int t0  = blockIdx.x * FPB;

    if (tid < FPB * MAXDEG) {
        const int tf = tid >> 4;
        s_src[tid] = adjsrc[(t0 + tf) * MAXDEG + (tid & 15)];
        s_wv[tid]  = adjw  [(t0 + tf) * MAXDEG + (tid & 15)];
    }
    if (tid >= 64 && tid < 64 + FPB) s_deg[tid - 64] = min(deg[t0 + tid - 64], MAXDEG);
    if (tid >= 128 && tid < 128 + FPB * WMAX) wmat[(tid - 128) / WMAX][(tid - 128) % WMAX] = 0.f;
    // zero agg pad rows (25..31 per frame)
    for (int i = tid; i < FPB * 7 * AGG_STRIDE; i += 512) {
        const int fr = i / (7 * AGG_STRIDE), rem = i % (7 * AGG_STRIDE);
        agg[fr * 32 * AGG_STRIDE + 25 * AGG_STRIDE + rem] = 0;
    }
    __syncthreads();

    // union source window over the 4 frames
    if (tid < 64) {
        const int fe = tid >> 4, e = tid & 15;
        const bool valid = e < s_deg[fe];
        int sv = valid ? s_src[tid] : 0x7fffffff;
        int sx = valid ? s_src[tid] : (int)0x80000000;
        #pragma unroll
        for (int off = 32; off; off >>= 1) {
            sv = min(sv, __shfl_down(sv, off));
            sx = max(sx, __shfl_down(sx, off));
        }
        if (tid == 0) {
            s_info[0] = sv;
            s_info[1] = (sx >= sv) ? (sx - sv + 1) : 0;
        }
    }
    __syncthreads();
    const int minS = s_info[0];
    const int nsrc = s_info[1];
    const bool windowed = (nsrc > 0) && (nsrc <= WMAX);
    if (windowed && tid < 64) {
        const int fe = tid >> 4, e = tid & 15;
        if (e < s_deg[fe]) atomicAdd(&wmat[fe][s_src[tid] - minS], s_wv[tid]);
    }
    __syncthreads();   // wmat ready

    // single-pass gather: thread owns one (row, c8) unit for all 4 frames
    if (tid < V * 16) {
        const int row = tid >> 4;
        const int c8  = (tid & 15) * 8;
        float a0[8] = {0,0,0,0,0,0,0,0}, a1[8] = {0,0,0,0,0,0,0,0};
        float a2[8] = {0,0,0,0,0,0,0,0}, a3[8] = {0,0,0,0,0,0,0,0};
        if (windowed) {
            const u16* hb = h + (size_t)minS * VC + row * C + c8;
            for (int s = 0; s < nsrc; s++) {
                const short8 hv = *reinterpret_cast<const short8*>(hb + (size_t)s * VC);
                const float w0 = wmat[0][s], w1 = wmat[1][s];
                const float w2 = wmat[2][s], w3 = wmat[3][s];
                #pragma unroll
                for (int j = 0; j < 8; j++) {
                    const float xv = bf2f((u16)hv[j]);
                    a0[j] = fmaf(w0, xv, a0[j]);
                    a1[j] = fmaf(w1, xv, a1[j]);
                    a2[j] = fmaf(w2, xv, a2[j]);
                    a3[j] = fmaf(w3, xv, a3[j]);
                }
            }
        } else {
            #pragma unroll
            for (int fe = 0; fe < FPB; fe++) {
                float* af = fe == 0 ? a0 : fe == 1 ? a1 : fe == 2 ? a2 : a3;
                for (int e = 0; e < s_deg[fe]; e++) {
                    const short8 hv = *reinterpret_cast<const short8*>(
                        h + (size_t)s_src[fe * MAXDEG + e] * VC + row * C + c8);
                    const float wv = s_wv[fe * MAXDEG + e];
                    #pragma unroll
                    for (int j = 0; j < 8; j++) af[j] = fmaf(wv, bf2f((u16)hv[j]), af[j]);
                }
            }
        }
        const float* accs[4] = {a0, a1, a2, a3};
        #pragma unroll
        for (int fe = 0; fe < FPB; fe++) {
            u32 pk[4];
            #pragma unroll
            for (int i = 0; i < 4; i++)
                pk[i] = (u32)f2bf(accs[fe][2 * i]) | ((u32)f2bf(accs[fe][2 * i + 1]) << 16);
            *reinterpret_cast<uint4*>(&agg[(fe * 32 + row) * AGG_STRIDE + c8]) =
                *reinterpret_cast<uint4*>(pk);
        }
    }
    __syncthreads();

    // Wt B-frags loaded only now (transient)
    short8 bfr[4];
    #pragma unroll
    for (int s = 0; s < 4; s++)
        bfr[s] = *reinterpret_cast<const short8*>(Wtsw + ((s * 4 + q) * C + col) * 8);
    const float btv = bt[col];

    #pragma unroll 1
    for (int fe = 0; fe < FPB; fe++) {
        floatx4 acc0 = {0,0,0,0}, acc1 = {0,0,0,0};
        const u16* ab = &agg[fe * 32 * AGG_STRIDE];
        #pragma unroll
        for (int s = 0; s < 4; s++) {
            const short8 a0 = *reinterpret_cast<const short8*>(&ab[ln * AGG_STRIDE + s * 32 + q * 8]);
            const short8 a1 = *reinterpret_cast<const short8*>(&ab[(16 + ln) * AGG_STRIDE + s * 32 + q * 8]);
            acc0 = __builtin_amdgcn_mfma_f32_16x16x32_bf16(a0, bfr[s], acc0, 0, 0, 0);
            acc1 = __builtin_amdgcn_mfma_f32_16x16x32_bf16(a1, bfr[s], acc1, 0, 0, 0);
        }
        float* op = out + (size_t)(t0 + fe) * VC;
        #pragma unroll
        for (int r = 0; r < 4; r++) {
            const float v = acc0[r] + btv;
            op[(q * 4 + r) * C + col] = v > 0.f ? v : 0.f;
        }
        #pragma unroll
        for (int r = 0; r < 4; r++) {
            const int row = 16 + q * 4 + r;
            if (row < V) {
                const float v = acc1[r] + btv;
                op[row * C + col] = v > 0.f ? v : 0.f;
            }
        }
    }
}

// ---------------------------------------------------------------- launcher
extern "C" void kernel_launch(void* const* d_in, const int* in_sizes, int n_in,
                              void* d_out, int out_size, void* d_ws, size_t ws_size,
                              hipStream_t stream) {
    const float* x     = (const float*)d_in[0];
    const float* A     = (const float*)d_in[1];
    const float* EI    = (const float*)d_in[2];
    const float* Ws    = (const float*)d_in[3];
    const float* bs    = (const float*)d_in[4];
    const float* Wt    = (const float*)d_in[5];
    const float* bt    = (const float*)d_in[6];
    const float* gamma = (const float*)d_in[7];
    const float* beta  = (const float*)d_in[8];
    const float* ew    = (const float*)d_in[9];
    const int*   eidx  = (const int*)d_in[10];
    const int E = in_sizes[9];

    char* ws = (char*)d_ws;
    u16*   h      = (u16*)(ws);                  // 15,360,000 B
    u16*   Wsw    = (u16*)(ws + 15360000);       // 98,304 B
    u16*   Wtsw   = (u16*)(ws + 15458304);       // 32,768 B
    u16*   Msw    = (u16*)(ws + 15491072);       // 6,144 B
    float* bsum   = (float*)(ws + 15497216);     // 512 B
    int*   deg    = (int*)(ws + 15497728);       // 9,600 B
    int*   adjsrc = (int*)(ws + 15507328);       // 153,600 B
    float* adjw   = (float*)(ws + 15660928);     // 153,600 B

    float* out = (float*)d_out;

    k_prep<<<(KS * C + 255) / 256, 256, 0, stream>>>(Ws, Wt, A, EI, bs, Wsw, Wtsw, Msw, bsum, deg);
    k_scatter<<<(E + 255) / 256, 256, 0, stream>>>(eidx, ew, E, deg, adjsrc, adjw);
    k_spatial<<<T_FRAMES, 512, 0, stream>>>(x, Wsw, Msw, bsum, gamma, beta, h);
    k_temporal<<<T_FRAMES / FPB, 512, 0, stream>>>(h, deg, adjsrc, adjw, Wtsw, bt, out);
}

// Round 11
// 136.159 us; speedup vs baseline: 1.1102x; 1.0163x over previous
//
#include <hip/hip_runtime.h>

#define T_FRAMES 2400
#define V 25
#define C 128
#define VC 3200          // V*C
#define NB 3
#define GN_EPS 1e-5f
#define MAXDEG 16
#define KS 384           // spatial GEMM1 K = 3*C
#define K2 96            // spatial GEMM2 K (3 branches x 32, v padded 25->32)
#define CSTR 136         // xt row stride (u16): 272B -> 2-way banks (free)
#define KSTR 104         // yb row stride (u16): 208B -> 2-way banks (free)
#define AGG_STRIDE 136   // agg row stride (u16)
#define FPB 4            // frames per block (temporal)
#define WMAX 48          // temporal source-window capacity

typedef __attribute__((ext_vector_type(8))) short short8;   // 8 bf16 (4 VGPR)
typedef __attribute__((ext_vector_type(4))) float floatx4;  // MFMA accum
typedef unsigned short u16;
typedef unsigned int u32;

__device__ __forceinline__ u16 f2bf(float f) {
    u32 u = __builtin_bit_cast(u32, f);
    u += 0x7FFFu + ((u >> 16) & 1u);          // RNE
    return (u16)(u >> 16);
}
__device__ __forceinline__ float bf2f(u16 h) {
    u32 u = ((u32)h) << 16;
    return __builtin_bit_cast(float, u);
}

// ------------------------------------------------------------------ prep
__global__ __launch_bounds__(256) void k_prep(
        const float* __restrict__ Ws, const float* __restrict__ Wt,
        const float* __restrict__ A, const float* __restrict__ EI,
        const float* __restrict__ bs,
        u16* __restrict__ Wsw, u16* __restrict__ Wtsw, u16* __restrict__ Msw,
        float* __restrict__ bsum, int* __restrict__ deg)
{
    const int idx = blockIdx.x * 256 + threadIdx.x;
    if (idx < KS * C) {
        const int j = idx & 7, n = (idx >> 3) & 127, kg = idx >> 10;
        const int k = kg * 8 + j;
        Wsw[idx] = f2bf(Ws[k * C + n]);
    }
    if (idx < C * C) {
        const int j = idx & 7, n = (idx >> 3) & 127, kg = idx >> 10;
        const int k = kg * 8 + j;
        Wtsw[idx] = f2bf(Wt[k * C + n]);
    }
    if (idx < 32 * K2) {
        const int u = idx / K2, r = idx % K2;
        const int i = r >> 5, v = r & 31;
        float val = 0.f;
        if (u < V && v < V) {
            const int a = (i * V + u) * V + v;
            val = A[a] * EI[a];
        }
        Msw[idx] = f2bf(val);
    }
    if (idx < C) bsum[idx] = bs[idx] + bs[C + idx] + bs[2 * C + idx];
    if (idx < T_FRAMES) deg[idx] = 0;
}

__global__ __launch_bounds__(256) void k_scatter(
        const int* __restrict__ eidx, const float* __restrict__ ew, int E,
        int* __restrict__ deg, int* __restrict__ adjsrc, float* __restrict__ adjw) {
    const int e = blockIdx.x * 256 + threadIdx.x;
    if (e >= E) return;
    const int s = eidx[e];
    const int d = eidx[E + e];
    const int slot = atomicAdd(&deg[d], 1);
    if (slot < MAXDEG) {
        adjsrc[d * MAXDEG + slot] = s;
        adjw  [d * MAXDEG + slot] = ew[e];
    }
}

// ---------------- spatial: all-MFMA, 1 frame/block, 3 barriers -----------
// 2400 blocks, XCD-swizzled: XCD k owns frames [300k, 300(k+1)) so h lands
// in the L2 that same-XCD temporal blocks will read. Register structure
// fits the hard 64-VGPR budget (rolled branch loop, transient mfr).
__global__ __launch_bounds__(512) void k_spatial(
        const float* __restrict__ x, const u16* __restrict__ Wsw,
        const u16* __restrict__ Msw, const float* __restrict__ bsum_g,
        const float* __restrict__ gamma_g, const float* __restrict__ beta_g,
        u16* __restrict__ h_g)
{
    __shared__ u16 xt[32 * CSTR];     // 8.7 KB  (bf16 x, rows 25-31 zero)
    __shared__ u16 yb[C * KSTR];      // 26.6 KB (Y^T: yb[d][k2])
    __shared__ float redS[8], redQ[8];

    const int tid = threadIdx.x;
    const int w   = tid >> 6;        // wave -> 16-col tile of d
    const int l   = tid & 63;
    const int q   = l >> 4;
    const int ln  = l & 15;
    const int col = w * 16 + ln;
    // XCD swizzle: consecutive blockIdx round-robin over 8 XCDs ->
    // give XCD (blk&7) the frame range [(blk&7)*300, ...).
    const int t   = (blockIdx.x & 7) * (T_FRAMES / 8) + (blockIdx.x >> 3);

    for (int i = tid; i < 7 * CSTR; i += 512) xt[25 * CSTR + i] = 0;

    const float bsv = bsum_g[col];

    // stage x[t] as bf16 into xt (400 threads x 8 u16)
    if (tid < 400) {
        const int srow = tid >> 4;
        const int sc0  = (tid & 15) * 8;
        const float* xp = x + (size_t)t * VC + srow * C + sc0;
        const float4 v0 = *(const float4*)xp;
        const float4 v1 = *(const float4*)(xp + 4);
        u32 pk[4];
        pk[0] = (u32)f2bf(v0.x) | ((u32)f2bf(v0.y) << 16);
        pk[1] = (u32)f2bf(v0.z) | ((u32)f2bf(v0.w) << 16);
        pk[2] = (u32)f2bf(v1.x) | ((u32)f2bf(v1.y) << 16);
        pk[3] = (u32)f2bf(v1.z) | ((u32)f2bf(v1.w) << 16);
        *reinterpret_cast<uint4*>(&xt[srow * CSTR + sc0]) = *reinterpret_cast<uint4*>(pk);
    }
    __syncthreads();   // (A) xt ready

    // ---- GEMM1^T: Y^T_i = Ws_i^T @ x^T, branch-sequential, loop ROLLED
    #pragma unroll 1
    for (int i = 0; i < 3; i++) {
        short8 wfr[4];
        #pragma unroll
        for (int s = 0; s < 4; s++)
            wfr[s] = *reinterpret_cast<const short8*>(
                Wsw + (((i * 4 + s) * 4 + q) * C + col) * 8);
        floatx4 ta = {0,0,0,0}, tb = {0,0,0,0};
        #pragma unroll
        for (int s = 0; s < 4; s++) {
            const short8 bx0 = *reinterpret_cast<const short8*>(&xt[ln * CSTR + s * 32 + q * 8]);
            const short8 bx1 = *reinterpret_cast<const short8*>(&xt[(16 + ln) * CSTR + s * 32 + q * 8]);
            ta = __builtin_amdgcn_mfma_f32_16x16x32_bf16(wfr[s], bx0, ta, 0, 0, 0);
            tb = __builtin_amdgcn_mfma_f32_16x16x32_bf16(wfr[s], bx1, tb, 0, 0, 0);
        }
        // D[m=q*4+r][n=ln]: d=w*16+q*4+r, v=ln (+16). Pad v>=25 computes 0.
        #pragma unroll
        for (int r = 0; r < 4; r++) {
            const int d = w * 16 + q * 4 + r;
            yb[d * KSTR + i * 32 + ln]      = f2bf(ta[r]);
            yb[d * KSTR + i * 32 + 16 + ln] = f2bf(tb[r]);
        }
    }

    // mfr loads issued BEFORE the barrier (no yb dependence)
    short8 mfr[2][3];
    #pragma unroll
    for (int tile = 0; tile < 2; tile++)
        #pragma unroll
        for (int i2 = 0; i2 < 3; i2++)
            mfr[tile][i2] = *reinterpret_cast<const short8*>(
                Msw + (tile * 16 + ln) * K2 + i2 * 32 + q * 8);
    __syncthreads();   // (B) yb ready

    // ---- GEMM2: h = M @ Y
    floatx4 h0 = {0,0,0,0}, h1 = {0,0,0,0};
    #pragma unroll
    for (int i2 = 0; i2 < 3; i2++) {
        const short8 b2 = *reinterpret_cast<const short8*>(&yb[col * KSTR + i2 * 32 + q * 8]);
        h0 = __builtin_amdgcn_mfma_f32_16x16x32_bf16(mfr[0][i2], b2, h0, 0, 0, 0);
        h1 = __builtin_amdgcn_mfma_f32_16x16x32_bf16(mfr[1][i2], b2, h1, 0, 0, 0);
    }

    // ---- bias + GN stats (mask pad rows >= 25)
    float s_p = 0.f, q_p = 0.f;
    #pragma unroll
    for (int r = 0; r < 4; r++) {
        h0[r] += bsv;
        s_p += h0[r]; q_p = fmaf(h0[r], h0[r], q_p);
    }
    #pragma unroll
    for (int r = 0; r < 4; r++) {
        h1[r] += bsv;
        if (q * 4 + r < 9) { s_p += h1[r]; q_p = fmaf(h1[r], h1[r], q_p); }
    }
    #pragma unroll
    for (int off = 32; off; off >>= 1) {
        s_p += __shfl_down(s_p, off);
        q_p += __shfl_down(q_p, off);
    }
    if (l == 0) { redS[w] = s_p; redQ[w] = q_p; }
    __syncthreads();   // (C) partials ready

    float S = 0.f, Q = 0.f;
    #pragma unroll
    for (int i = 0; i < 8; i++) { S += redS[i]; Q += redQ[i]; }
    const float mu  = S / (float)VC;
    const float var = Q / (float)VC - mu * mu;
    const float rs  = rsqrtf(fmaxf(var, 0.f) + GN_EPS);

    u16* hp = h_g + (size_t)t * VC;
    #pragma unroll
    for (int r = 0; r < 4; r++) {
        const int idx = (q * 4 + r) * C + col;
        const float v = (h0[r] - mu) * rs * gamma_g[idx] + beta_g[idx];
        hp[idx] = f2bf(v > 0.f ? v : 0.f);
    }
    #pragma unroll
    for (int r = 0; r < 4; r++) {
        const int row = 16 + q * 4 + r;
        if (row < V) {
            const int idx = row * C + col;
            const float v = (h1[r] - mu) * rs * gamma_g[idx] + beta_g[idx];
            hp[idx] = f2bf(v > 0.f ? v : 0.f);
        }
    }
}

// ------------------- temporal: windowed gather-sum + MFMA + bias + ReLU
// 600 blocks x 4 frames, XCD-swizzled to match k_spatial's frame->XCD map:
// gather reads hit the local XCD L2 (per-XCD h slice = 1.92 MB < 4 MB).
// out stores nontemporal (no reuse; don't evict the h slice).
__global__ __launch_bounds__(512) void k_temporal(
        const u16* __restrict__ h, const int* __restrict__ deg,
        const int* __restrict__ adjsrc, const float* __restrict__ adjw,
        const u16* __restrict__ Wtsw, const float* __restrict__ bt,
        float* __restrict__ out)
{
    __shared__ u16   agg[FPB * 32 * AGG_STRIDE];   // 34.8 KB
    __shared__ float wmat[FPB][WMAX];
    __shared__ int   s_src[FPB * MAXDEG];
    __shared__ float s_wv[FPB * MAXDEG];
    __shared__ int   s_deg[FPB];
    __shared__ int   s_info[2];                    // minS, nsrc

    const int tid = threadIdx.x;
    const int w   = tid >> 6;
    const int l   = tid & 63;
    const int q   = l >> 4;
    const int ln  = l & 15;
    const int col = w * 16 + ln;
    // XCD swizzle matching k_spatial: XCD (blk&7) owns frame-groups
    // [(blk&7)*75, ...) i.e. frames [(blk&7)*300, ...).
    const int t0  = ((blockIdx.x & 7) * (T_FRAMES / FPB / 8) + (blockIdx.x >> 3)) * FPB;

    if (tid < FPB * MAXDEG) {
        const int tf = tid >> 4;
        s_src[tid] = adjsrc[(t0 + tf) * MAXDEG + (tid & 15)];
        s_wv[tid]  = adjw  [(t0 + tf) * MAXDEG + (tid & 15)];
    }
    if (tid >= 64 && tid < 64 + FPB) s_deg[tid - 64] = min(deg[t0 + tid - 64], MAXDEG);
    if (tid >= 128 && tid < 128 + FPB * WMAX) wmat[(tid - 128) / WMAX][(tid - 128) % WMAX] = 0.f;
    // zero agg pad rows (25..31 per frame)
    for (int i = tid; i < FPB * 7 * AGG_STRIDE; i += 512) {
        const int fr = i / (7 * AGG_STRIDE), rem = i % (7 * AGG_STRIDE);
        agg[fr * 32 * AGG_STRIDE + 25 * AGG_STRIDE + rem] = 0;
    }
    __syncthreads();

    // union source window over the 4 frames
    if (tid < 64) {
        const int fe = tid >> 4, e = tid & 15;
        const bool valid = e < s_deg[fe];
        int sv = valid ? s_src[tid] : 0x7fffffff;
        int sx = valid ? s_src[tid] : (int)0x80000000;
        #pragma unroll
        for (int off = 32; off; off >>= 1) {
            sv = min(sv, __shfl_down(sv, off));
            sx = max(sx, __shfl_down(sx, off));
        }
        if (tid == 0) {
            s_info[0] = sv;
            s_info[1] = (sx >= sv) ? (sx - sv + 1) : 0;
        }
    }
    __syncthreads();
    const int minS = s_info[0];
    const int nsrc = s_info[1];
    const bool windowed = (nsrc > 0) && (nsrc <= WMAX);
    if (windowed && tid < 64) {
        const int fe = tid >> 4, e = tid & 15;
        if (e < s_deg[fe]) atomicAdd(&wmat[fe][s_src[tid] - minS], s_wv[tid]);
    }
    __syncthreads();   // wmat ready

    // single-pass gather: thread owns one (row, c8) unit for all 4 frames
    if (tid < V * 16) {
        const int row = tid >> 4;
        const int c8  = (tid & 15) * 8;
        float a0[8] = {0,0,0,0,0,0,0,0}, a1[8] = {0,0,0,0,0,0,0,0};
        float a2[8] = {0,0,0,0,0,0,0,0}, a3[8] = {0,0,0,0,0,0,0,0};
        if (windowed) {
            const u16* hb = h + (size_t)minS * VC + row * C + c8;
            for (int s = 0; s < nsrc; s++) {
                const short8 hv = *reinterpret_cast<const short8*>(hb + (size_t)s * VC);
                const float w0 = wmat[0][s], w1 = wmat[1][s];
                const float w2 = wmat[2][s], w3 = wmat[3][s];
                #pragma unroll
                for (int j = 0; j < 8; j++) {
                    const float xv = bf2f((u16)hv[j]);
                    a0[j] = fmaf(w0, xv, a0[j]);
                    a1[j] = fmaf(w1, xv, a1[j]);
                    a2[j] = fmaf(w2, xv, a2[j]);
                    a3[j] = fmaf(w3, xv, a3[j]);
                }
            }
        } else {
            #pragma unroll
            for (int fe = 0; fe < FPB; fe++) {
                float* af = fe == 0 ? a0 : fe == 1 ? a1 : fe == 2 ? a2 : a3;
                for (int e = 0; e < s_deg[fe]; e++) {
                    const short8 hv = *reinterpret_cast<const short8*>(
                        h + (size_t)s_src[fe * MAXDEG + e] * VC + row * C + c8);
                    const float wv = s_wv[fe * MAXDEG + e];
                    #pragma unroll
                    for (int j = 0; j < 8; j++) af[j] = fmaf(wv, bf2f((u16)hv[j]), af[j]);
                }
            }
        }
        const float* accs[4] = {a0, a1, a2, a3};
        #pragma unroll
        for (int fe = 0; fe < FPB; fe++) {
            u32 pk[4];
            #pragma unroll
            for (int i = 0; i < 4; i++)
                pk[i] = (u32)f2bf(accs[fe][2 * i]) | ((u32)f2bf(accs[fe][2 * i + 1]) << 16);
            *reinterpret_cast<uint4*>(&agg[(fe * 32 + row) * AGG_STRIDE + c8]) =
                *reinterpret_cast<uint4*>(pk);
        }
    }
    __syncthreads();

    // Wt B-frags loaded only now (transient)
    short8 bfr[4];
    #pragma unroll
    for (int s = 0; s < 4; s++)
        bfr[s] = *reinterpret_cast<const short8*>(Wtsw + ((s * 4 + q) * C + col) * 8);
    const float btv = bt[col];

    #pragma unroll 1
    for (int fe = 0; fe < FPB; fe++) {
        floatx4 acc0 = {0,0,0,0}, acc1 = {0,0,0,0};
        const u16* ab = &agg[fe * 32 * AGG_STRIDE];
        #pragma unroll
        for (int s = 0; s < 4; s++) {
            const short8 a0 = *reinterpret_cast<const short8*>(&ab[ln * AGG_STRIDE + s * 32 + q * 8]);
            const short8 a1 = *reinterpret_cast<const short8*>(&ab[(16 + ln) * AGG_STRIDE + s * 32 + q * 8]);
            acc0 = __builtin_amdgcn_mfma_f32_16x16x32_bf16(a0, bfr[s], acc0, 0, 0, 0);
            acc1 = __builtin_amdgcn_mfma_f32_16x16x32_bf16(a1, bfr[s], acc1, 0, 0, 0);
        }
        float* op = out + (size_t)(t0 + fe) * VC;
        #pragma unroll
        for (int r = 0; r < 4; r++) {
            const float v = acc0[r] + btv;
            __builtin_nontemporal_store(v > 0.f ? v : 0.f, &op[(q * 4 + r) * C + col]);
        }
        #pragma unroll
        for (int r = 0; r < 4; r++) {
            const int row = 16 + q * 4 + r;
            if (row < V) {
                const float v = acc1[r] + btv;
                __builtin_nontemporal_store(v > 0.f ? v : 0.f, &op[row * C + col]);
            }
        }
    }
}

// ---------------------------------------------------------------- launcher
extern "C" void kernel_launch(void* const* d_in, const int* in_sizes, int n_in,
                              void* d_out, int out_size, void* d_ws, size_t ws_size,
                              hipStream_t stream) {
    const float* x     = (const float*)d_in[0];
    const float* A     = (const float*)d_in[1];
    const float* EI    = (const float*)d_in[2];
    const float* Ws    = (const float*)d_in[3];
    const float* bs    = (const float*)d_in[4];
    const float* Wt    = (const float*)d_in[5];
    const float* bt    = (const float*)d_in[6];
    const float* gamma = (const float*)d_in[7];
    const float* beta  = (const float*)d_in[8];
    const float* ew    = (const float*)d_in[9];
    const int*   eidx  = (const int*)d_in[10];
    const int E = in_sizes[9];

    char* ws = (char*)d_ws;
    u16*   h      = (u16*)(ws);                  // 15,360,000 B
    u16*   Wsw    = (u16*)(ws + 15360000);       // 98,304 B
    u16*   Wtsw   = (u16*)(ws + 15458304);       // 32,768 B
    u16*   Msw    = (u16*)(ws + 15491072);       // 6,144 B
    float* bsum   = (float*)(ws + 15497216);     // 512 B
    int*   deg    = (int*)(ws + 15497728);       // 9,600 B
    int*   adjsrc = (int*)(ws + 15507328);       // 153,600 B
    float* adjw   = (float*)(ws + 15660928);     // 153,600 B

    float* out = (float*)d_out;

    k_prep<<<(KS * C + 255) / 256, 256, 0, stream>>>(Ws, Wt, A, EI, bs, Wsw, Wtsw, Msw, bsum, deg);
    k_scatter<<<(E + 255) / 256, 256, 0, stream>>>(eidx, ew, E, deg, adjsrc, adjw);
    k_spatial<<<T_FRAMES, 512, 0, stream>>>(x, Wsw, Msw, bsum, gamma, beta, h);
    k_temporal<<<T_FRAMES / FPB, 512, 0, stream>>>(h, deg, adjsrc, adjw, Wtsw, bt, out);
}